// Round 6
// baseline (140.638 us; speedup 1.0000x reference)
//
#include <hip/hip_runtime.h>
#include <hip/hip_fp16.h>

namespace {
constexpr int A_N = 96;
constexpr int U_N = 128;
constexpr int V_N = 128;
constexpr int W_N = 128;
constexpr int H_N = 128;
constexpr int NSTEPS = 128;
constexpr float T_HALF = 89.80256121069154f;
constexpr float DT = 1.4031650189170554f;   // 2*T/NSTEPS
constexpr float INV_DT = 1.0f / DT;
constexpr int PAD = 6;                      // zero border: covers range slop
constexpr int WP = W_N + 2 * PAD;           // 140 padded columns per row
constexpr int ROW_BYTES = WP * 256;         // x-stride in bytes (f16 column = 256 B)
constexpr size_t VOLP_COLS = (size_t)WP * WP;          // 19600 columns
constexpr size_t VOLP_BYTES = VOLP_COLS * 256;         // ~5.02 MB
constexpr size_t SINO = (size_t)U_N * A_N * V_N;       // 1.57M floats
}

typedef __attribute__((ext_vector_type(4))) unsigned int u32x4;

// ---- pack two floats -> half2 bits ----
__device__ __forceinline__ unsigned int packh2(float a, float b) {
    return (unsigned int)__half_as_ushort(__float2half_rn(a)) |
           ((unsigned int)__half_as_ushort(__float2half_rn(b)) << 16);
}

// ---- pre-pass: fp32 volume -> padded f16 volume (zero border of PAD cols) ----
__global__ __launch_bounds__(256) void vol_pad_f16(
    const float* __restrict__ vol, unsigned int* __restrict__ volp)
{
    const int idx = blockIdx.x * 256 + threadIdx.x;    // WP*WP*16 threads
    if (idx >= (int)(VOLP_COLS * 16)) return;
    const int zo  = idx & 15;
    const int col = idx >> 4;
    const int yp = col % WP;
    const int xp = col / WP;
    const int x = xp - PAD;
    const int y = yp - PAD;
    uint4 o = make_uint4(0u, 0u, 0u, 0u);
    if ((unsigned)x < 128u && (unsigned)y < 128u) {
        const float* src = vol + (((size_t)x * 128 + y) << 7) + zo * 8;
        const float4 f0 = *(const float4*)(src);
        const float4 f1 = *(const float4*)(src + 4);
        o.x = packh2(f0.x, f0.y);
        o.y = packh2(f0.z, f0.w);
        o.z = packh2(f1.x, f1.y);
        o.w = packh2(f1.z, f1.w);
    }
    *(uint4*)((char*)volp + (size_t)col * 256 + zo * 16) = o;
}

// ---- main projector: ONE WAVE = ONE RAY.
//      lane = (corner c = lane>>4, z-chunk k = lane&15).
//      Per step: single global_load_dwordx4 covers the whole 4-corner
//      128-z footprint (lanes 0-31 and 32-63 each 512 B contiguous).
//      Per-lane corner weight; corner sum via shfl_xor butterfly at end. ----
__global__ __launch_bounds__(256) void joseph_fwd_wave(
    const unsigned short* __restrict__ volp,
    const float* __restrict__ angles,
    float* __restrict__ out)
{
    const int lane = threadIdx.x & 63;
    const int wv   = threadIdx.x >> 6;       // wave in block (0..3)
    const int u_i  = blockIdx.x * 4 + wv;    // ray u index
    const int a    = blockIdx.y;

    const int c = lane >> 4;                 // corner slot: 0=(x0,y0) 1=(x0,y1) 2=(x1,y0) 3=(x1,y1)
    const int k = lane & 15;                 // z-chunk (8 f16 each)
    // corner byte offset: y+1 -> +256 (contiguous column), x+1 -> +ROW_BYTES
    const int laneOff = ((c & 1) << 8) + ((c >> 1) * ROW_BYTES) + (k << 4);
    // corner weight = (sx*fx+bx) * (sy*fy+by)
    const float sxw = (c >> 1) ? 1.f : -1.f;
    const float bxw = (c >> 1) ? 0.f : 1.f;
    const float syw = (c & 1) ? 1.f : -1.f;
    const float byw = (c & 1) ? 0.f : 1.f;

    const float ang = angles[a];
    const float cv = cosf(ang);
    const float sv = sinf(ang);
    const float up = (float)u_i - 63.5f;
    const float xb = fmaf(-up, sv, 63.5f);
    const float yb = fmaf( up, cv, 63.5f);

    // valid-step range: xi,yi in (-1,128); +-2-step slop < PAD=6
    float tlo = -2.f * T_HALF, thi = 2.f * T_HALF;
    if (fabsf(cv) > 1e-6f) {
        const float ta = (-1.f - xb) / cv, tb = (128.f - xb) / cv;
        tlo = fmaxf(tlo, fminf(ta, tb));
        thi = fminf(thi, fmaxf(ta, tb));
    } else if (xb <= -1.f || xb >= 128.f) { thi = tlo - 1.f; }
    if (fabsf(sv) > 1e-6f) {
        const float ta = (-1.f - yb) / sv, tb = (128.f - yb) / sv;
        tlo = fmaxf(tlo, fminf(ta, tb));
        thi = fminf(thi, fmaxf(ta, tb));
    } else if (yb <= -1.f || yb >= 128.f) { thi = tlo - 1.f; }
    const int ilo = (int)floorf(fmaf(tlo + T_HALF, INV_DT, -0.5f)) - 1;
    const int ihi = (int)ceilf (fmaf(thi + T_HALF, INV_DT, -0.5f)) + 1;
    const int lo = min(max(ilo, 0), NSTEPS);
    const int hi = min(max(ihi + 1, 0), NSTEPS);

    const char* __restrict__ volc = (const char*)volp;

    __half2 hacc[4];
    float accf[8];
#pragma unroll
    for (int j = 0; j < 4; ++j) hacc[j] = __float2half2_rn(0.f);
#pragma unroll
    for (int j = 0; j < 8; ++j) accf[j] = 0.f;

    int kc = 0;
    for (int i = lo; i < hi; ++i) {
        const float tf = fmaf((float)i + 0.5f, DT, -T_HALF);
        const float xi = fmaf(tf, cv, xb);
        const float yi = fmaf(tf, sv, yb);
        const float fx0 = floorf(xi);
        const float fy0 = floorf(yi);
        const float fx = xi - fx0;
        const float fy = yi - fy0;
        const int x0 = (int)fx0;
        const int y0 = (int)fy0;
        const int off = (((x0 + PAD) * WP + (y0 + PAD)) << 8) + laneOff;

        const u32x4 q = *(const u32x4*)(volc + off);

        const float w = fmaf(sxw, fx, bxw) * fmaf(syw, fy, byw);
        const __half2 wh = __float2half2_rn(w);
        hacc[0] = __hfma2(wh, __builtin_bit_cast(__half2, (unsigned int)q[0]), hacc[0]);
        hacc[1] = __hfma2(wh, __builtin_bit_cast(__half2, (unsigned int)q[1]), hacc[1]);
        hacc[2] = __hfma2(wh, __builtin_bit_cast(__half2, (unsigned int)q[2]), hacc[2]);
        hacc[3] = __hfma2(wh, __builtin_bit_cast(__half2, (unsigned int)q[3]), hacc[3]);

        if (((++kc) & 3) == 0) {              // flush every 4 steps (fp16 headroom)
#pragma unroll
            for (int j = 0; j < 4; ++j) {
                const float2 f = __half22float2(hacc[j]);
                accf[2 * j]     += f.x;
                accf[2 * j + 1] += f.y;
                hacc[j] = __float2half2_rn(0.f);
            }
        }
    }
#pragma unroll
    for (int j = 0; j < 4; ++j) {             // final flush
        const float2 f = __half22float2(hacc[j]);
        accf[2 * j]     += f.x;
        accf[2 * j + 1] += f.y;
    }

    // corner-sum butterfly: xor 16 merges y-corners, xor 32 merges x-corners
#pragma unroll
    for (int j = 0; j < 8; ++j) {
        accf[j] += __shfl_xor(accf[j], 16);
        accf[j] += __shfl_xor(accf[j], 32);
    }

    // lane group c==0 writes z 8k..8k+3, c==1 writes z 8k+4..8k+7
    float* op = out + ((size_t)u_i * A_N + a) * V_N + 8 * k;
    if (c == 0) {
        *(float4*)(op) = make_float4(accf[0] * DT, accf[1] * DT, accf[2] * DT, accf[3] * DT);
    } else if (c == 1) {
        *(float4*)(op + 4) = make_float4(accf[4] * DT, accf[5] * DT, accf[6] * DT, accf[7] * DT);
    }
}

// ---- fallback: fp32 volume, no workspace needed ----
__global__ __launch_bounds__(256) void joseph_fwd_f32(
    const float* __restrict__ vol,
    const float* __restrict__ angles,
    float* __restrict__ out)
{
    const int zo  = threadIdx.x & 15;
    const int r   = threadIdx.x >> 4;
    const int u_i = blockIdx.x * 16 + r;
    const int a   = blockIdx.y;

    const float ang = angles[a];
    const float c = cosf(ang);
    const float s = sinf(ang);
    const float u = (float)u_i - 63.5f;
    const float xb = fmaf(-u, s, 63.5f);
    const float yb = fmaf( u, c, 63.5f);

    const float* volz = vol + 8 * zo;
    float4 accA = make_float4(0.f, 0.f, 0.f, 0.f);
    float4 accB = make_float4(0.f, 0.f, 0.f, 0.f);

    for (int i = 0; i < NSTEPS; ++i) {
        const float t  = fmaf((float)i + 0.5f, DT, -T_HALF);
        const float xi = fmaf(t, c, xb);
        const float yi = fmaf(t, s, yb);
        const float fx0f = floorf(xi);
        const float fy0f = floorf(yi);
        const int x0 = (int)fx0f;
        const int y0 = (int)fy0f;
        const float fx = xi - fx0f;
        const float fy = yi - fy0f;
        const int x1 = x0 + 1;
        const int y1 = y0 + 1;
        const float wx0 = (x0 >= 0 && x0 < W_N) ? (1.f - fx) : 0.f;
        const float wx1 = (x1 >= 0 && x1 < W_N) ? fx : 0.f;
        const float wy0 = (y0 >= 0 && y0 < H_N) ? (1.f - fy) : 0.f;
        const float wy1 = (y1 >= 0 && y1 < H_N) ? fy : 0.f;
        if ((wx0 + wx1) == 0.f || (wy0 + wy1) == 0.f) continue;
        const int cx0 = min(max(x0, 0), W_N - 1);
        const int cx1 = min(max(x1, 0), W_N - 1);
        const int cy0 = min(max(y0, 0), H_N - 1);
        const int cy1 = min(max(y1, 0), H_N - 1);
        const float* p00 = volz + ((cx0 * H_N + cy0) << 7);
        const float* p01 = volz + ((cx1 * H_N + cy0) << 7);
        const float* p10 = volz + ((cx0 * H_N + cy1) << 7);
        const float* p11 = volz + ((cx1 * H_N + cy1) << 7);
        const float4 v00a = *(const float4*)(p00);
        const float4 v00b = *(const float4*)(p00 + 4);
        const float4 v01a = *(const float4*)(p01);
        const float4 v01b = *(const float4*)(p01 + 4);
        const float4 v10a = *(const float4*)(p10);
        const float4 v10b = *(const float4*)(p10 + 4);
        const float4 v11a = *(const float4*)(p11);
        const float4 v11b = *(const float4*)(p11 + 4);
        const float w00 = wx0 * wy0, w01 = wx1 * wy0, w10 = wx0 * wy1, w11 = wx1 * wy1;
        accA.x = fmaf(w00, v00a.x, fmaf(w01, v01a.x, fmaf(w10, v10a.x, fmaf(w11, v11a.x, accA.x))));
        accA.y = fmaf(w00, v00a.y, fmaf(w01, v01a.y, fmaf(w10, v10a.y, fmaf(w11, v11a.y, accA.y))));
        accA.z = fmaf(w00, v00a.z, fmaf(w01, v01a.z, fmaf(w10, v10a.z, fmaf(w11, v11a.z, accA.z))));
        accA.w = fmaf(w00, v00a.w, fmaf(w01, v01a.w, fmaf(w10, v10a.w, fmaf(w11, v11a.w, accA.w))));
        accB.x = fmaf(w00, v00b.x, fmaf(w01, v01b.x, fmaf(w10, v10b.x, fmaf(w11, v11b.x, accB.x))));
        accB.y = fmaf(w00, v00b.y, fmaf(w01, v01b.y, fmaf(w10, v10b.y, fmaf(w11, v11b.y, accB.y))));
        accB.z = fmaf(w00, v00b.z, fmaf(w01, v01b.z, fmaf(w10, v10b.z, fmaf(w11, v11b.z, accB.z))));
        accB.w = fmaf(w00, v00b.w, fmaf(w01, v01b.w, fmaf(w10, v10b.w, fmaf(w11, v11b.w, accB.w))));
    }

    float* op = out + ((size_t)u_i * A_N + a) * V_N + 8 * zo;
    *(float4*)(op)     = make_float4(accA.x * DT, accA.y * DT, accA.z * DT, accA.w * DT);
    *(float4*)(op + 4) = make_float4(accB.x * DT, accB.y * DT, accB.z * DT, accB.w * DT);
}

extern "C" void kernel_launch(void* const* d_in, const int* in_sizes, int n_in,
                              void* d_out, int out_size, void* d_ws, size_t ws_size,
                              hipStream_t stream) {
    const float* vol    = (const float*)d_in[0];
    const float* angles = (const float*)d_in[1];
    float* out          = (float*)d_out;

    const int pad_blocks = (int)((VOLP_COLS * 16 + 255) / 256);

    if (ws_size >= VOLP_BYTES) {
        unsigned int* volp = (unsigned int*)d_ws;
        hipLaunchKernelGGL(vol_pad_f16, dim3(pad_blocks), dim3(256), 0, stream, vol, volp);
        dim3 grid(U_N / 4, A_N);              // 32 x 96 blocks, 4 waves (rays) each
        hipLaunchKernelGGL(joseph_fwd_wave, grid, dim3(256), 0, stream,
                           (const unsigned short*)volp, angles, out);
    } else {
        dim3 grid(U_N / 16, A_N);
        hipLaunchKernelGGL(joseph_fwd_f32, grid, dim3(256), 0, stream, vol, angles, out);
    }
}

// Round 7
// 116.575 us; speedup vs baseline: 1.2064x; 1.2064x over previous
//
#include <hip/hip_runtime.h>
#include <hip/hip_fp16.h>

namespace {
constexpr int A_N = 96;
constexpr int U_N = 128;
constexpr int V_N = 128;
constexpr int W_N = 128;
constexpr int H_N = 128;
constexpr int NSTEPS = 128;
constexpr float T_HALF = 89.80256121069154f;
constexpr float DT = 1.4031650189170554f;   // 2*T/NSTEPS
constexpr float INV_DT = 1.0f / DT;
constexpr int PAD = 6;                      // zero border: covers range slop + unroll alignment
constexpr int WP = W_N + 2 * PAD;           // 140 padded columns per row
constexpr int ROW_BYTES = WP * 256;         // x-stride in bytes (f16 column = 256 B)
constexpr int ZT = 8;                       // z-threads per ray (16 z-values each)
constexpr int RAYS_PER_WAVE = 8;            // wave = 8 rays x 8 z (VALU amortized, line-minimal)
constexpr int WAVES_PER_BLOCK = 4;          // 256-thr blocks: beats the per-CU workgroup-slot cap
constexpr int RAYS_PER_BLOCK = RAYS_PER_WAVE * WAVES_PER_BLOCK;   // 32
constexpr int BLOCK_THREADS = 256;
constexpr size_t VOLP_COLS = (size_t)WP * WP;          // 19600 columns
constexpr size_t VOLP_BYTES = VOLP_COLS * 256;         // ~5.02 MB
constexpr size_t SINO = (size_t)U_N * A_N * V_N;       // 1.57M floats
}

typedef __attribute__((ext_vector_type(4))) unsigned int u32x4;

// ---- pack two floats -> half2 bits ----
__device__ __forceinline__ unsigned int packh2(float a, float b) {
    return (unsigned int)__half_as_ushort(__float2half_rn(a)) |
           ((unsigned int)__half_as_ushort(__float2half_rn(b)) << 16);
}

// ---- pre-pass: fp32 volume -> padded f16 volume (zero border of PAD cols) ----
__global__ __launch_bounds__(256) void vol_pad_f16(
    const float* __restrict__ vol, unsigned int* __restrict__ volp)
{
    const int idx = blockIdx.x * 256 + threadIdx.x;    // WP*WP*16 threads
    if (idx >= (int)(VOLP_COLS * 16)) return;
    const int zo  = idx & 15;
    const int col = idx >> 4;
    const int yp = col % WP;
    const int xp = col / WP;
    const int x = xp - PAD;
    const int y = yp - PAD;
    uint4 o = make_uint4(0u, 0u, 0u, 0u);
    if ((unsigned)x < 128u && (unsigned)y < 128u) {
        const float* src = vol + (((size_t)x * 128 + y) << 7) + zo * 8;
        const float4 f0 = *(const float4*)(src);
        const float4 f1 = *(const float4*)(src + 4);
        o.x = packh2(f0.x, f0.y);
        o.y = packh2(f0.z, f0.w);
        o.z = packh2(f1.x, f1.y);
        o.w = packh2(f1.z, f1.w);
    }
    *(uint4*)((char*)volp + (size_t)col * 256 + zo * 16) = o;
}

// ---- issue 4 16-B loads from one column-pair base (asm: compiler cannot
//      re-serialize; registers forced live; no implicit waitcnt emitted) ----
#define ISSUE4(p, q0, q1, q2, q3)                                        \
    asm volatile("global_load_dwordx4 %0, %4, off\n\t"                   \
                 "global_load_dwordx4 %1, %4, off offset:128\n\t"        \
                 "global_load_dwordx4 %2, %4, off offset:256\n\t"        \
                 "global_load_dwordx4 %3, %4, off offset:384"            \
                 : "=&v"(q0), "=&v"(q1), "=&v"(q2), "=&v"(q3)            \
                 : "v"(p))

// counted waits: keep the other batch in flight (T4 pattern); sched_barrier
// stops hipcc hoisting dependent ALU above the wait (guide rule #18)
#define WAIT_VM8()  do { asm volatile("s_waitcnt vmcnt(8)" ::: "memory"); \
                         __builtin_amdgcn_sched_barrier(0); } while (0)
#define WAIT_VM0()  do { asm volatile("s_waitcnt vmcnt(0)" ::: "memory"); \
                         __builtin_amdgcn_sched_barrier(0); } while (0)

// ---- main projector: wave = 8 rays x 8 z (16 z-values/thread, two contiguous
//      half-columns -> line-minimal); 4 waves per 256-thr block to beat the
//      per-CU workgroup-slot cap; asm-pipelined loads, counted vmcnt ----
__global__ __launch_bounds__(BLOCK_THREADS, 4) void joseph_fwd_inc(
    const unsigned short* __restrict__ volp,
    const float* __restrict__ angles,
    float* __restrict__ dst, float scale)
{
    const int zo = threadIdx.x & (ZT - 1);        // z-group within wave
    const int r  = (threadIdx.x >> 3) & 7;        // ray within wave (0..7)
    const int wv = threadIdx.x >> 6;              // wave within block (0..3)
    // center-first tile order over 4 tiles: {1,2,0,3}
    const int bx = (int)blockIdx.x;
    const int xt = (bx == 0) ? 1 : (bx == 1) ? 2 : (bx == 2) ? 0 : 3;
    const int u_i = xt * RAYS_PER_BLOCK + wv * RAYS_PER_WAVE + r;
    const int a   = blockIdx.y;

    const int spseg = NSTEPS / gridDim.z;
    const int i0 = blockIdx.z * spseg;
    const int i1 = i0 + spseg;

    const float ang = angles[a];
    const float cv = cosf(ang);
    const float sv = sinf(ang);
    const float up = (float)u_i - 63.5f;
    const float xb = fmaf(-up, sv, 63.5f);
    const float yb = fmaf( up, cv, 63.5f);

    // valid-step range: xi,yi in (-1,128); +-2-step slop + 1 alignment step < PAD=6
    float tlo = -2.f * T_HALF, thi = 2.f * T_HALF;
    if (fabsf(cv) > 1e-6f) {
        const float ta = (-1.f - xb) / cv, tb = (128.f - xb) / cv;
        tlo = fmaxf(tlo, fminf(ta, tb));
        thi = fminf(thi, fmaxf(ta, tb));
    } else if (xb <= -1.f || xb >= 128.f) { thi = tlo - 1.f; }
    if (fabsf(sv) > 1e-6f) {
        const float ta = (-1.f - yb) / sv, tb = (128.f - yb) / sv;
        tlo = fmaxf(tlo, fminf(ta, tb));
        thi = fminf(thi, fmaxf(ta, tb));
    } else if (yb <= -1.f || yb >= 128.f) { thi = tlo - 1.f; }
    const int ilo = (int)floorf(fmaf(tlo + T_HALF, INV_DT, -0.5f)) - 1;
    const int ihi = (int)ceilf (fmaf(thi + T_HALF, INV_DT, -0.5f)) + 1;
    int lo = min(max(ilo, i0), i1);
    int hi = min(max(ihi + 1, i0), i1);
    lo &= ~1;                                  // even-align down (pad-safe)
    hi = (hi + 1) & ~1;                        // even-align up (spseg even -> hi<=i1)

    const char* __restrict__ volc = (const char*)volp;
    const int laneb = zo << 4;                 // contiguous 16 B per z-thread within half-column

    __half2 hacc[8];
    float accf[16];
#pragma unroll
    for (int j = 0; j < 8; ++j) hacc[j] = __float2half2_rn(0.f);
#pragma unroll
    for (int k = 0; k < 16; ++k) accf[k] = 0.f;

    auto base_of = [&](float i_f, float& fx, float& fy) -> const char* {
        const float tf = fmaf(i_f + 0.5f, DT, -T_HALF);
        const float xi = fmaf(tf, cv, xb);
        const float yi = fmaf(tf, sv, yb);
        const float fx0 = floorf(xi);
        const float fy0 = floorf(yi);
        fx = xi - fx0;
        fy = yi - fy0;
        const int x0 = (int)fx0;
        const int y0 = (int)fy0;
        return volc + ((((x0 + PAD) * WP + (y0 + PAD)) << 8) + laneb);
    };

    // q order: {00lo,00hi, 01lo,01hi, 10lo,10hi, 11lo,11hi}
    auto cons = [&](u32x4 q00l, u32x4 q00h, u32x4 q01l, u32x4 q01h,
                    u32x4 q10l, u32x4 q10h, u32x4 q11l, u32x4 q11h,
                    float fx, float fy) {
        const float wx0 = 1.f - fx;
        const float wy0 = 1.f - fy;
        const __half2 w00 = __float2half2_rn(wx0 * wy0);
        const __half2 w01 = __float2half2_rn(wx0 * fy);
        const __half2 w10 = __float2half2_rn(fx  * wy0);
        const __half2 w11 = __float2half2_rn(fx  * fy);
#pragma unroll
        for (int j = 0; j < 4; ++j) {
            hacc[j] = __hfma2(w00, __builtin_bit_cast(__half2, (unsigned int)q00l[j]), hacc[j]);
            hacc[j] = __hfma2(w01, __builtin_bit_cast(__half2, (unsigned int)q01l[j]), hacc[j]);
            hacc[j] = __hfma2(w10, __builtin_bit_cast(__half2, (unsigned int)q10l[j]), hacc[j]);
            hacc[j] = __hfma2(w11, __builtin_bit_cast(__half2, (unsigned int)q11l[j]), hacc[j]);
            hacc[4 + j] = __hfma2(w00, __builtin_bit_cast(__half2, (unsigned int)q00h[j]), hacc[4 + j]);
            hacc[4 + j] = __hfma2(w01, __builtin_bit_cast(__half2, (unsigned int)q01h[j]), hacc[4 + j]);
            hacc[4 + j] = __hfma2(w10, __builtin_bit_cast(__half2, (unsigned int)q10h[j]), hacc[4 + j]);
            hacc[4 + j] = __hfma2(w11, __builtin_bit_cast(__half2, (unsigned int)q11h[j]), hacc[4 + j]);
        }
    };

    auto flush = [&]() {
#pragma unroll
        for (int j = 0; j < 8; ++j) {
            const float2 f = __half22float2(hacc[j]);
            accf[2 * j]     += f.x;
            accf[2 * j + 1] += f.y;
            hacc[j] = __float2half2_rn(0.f);
        }
    };

    // asm-pipelined main loop: batch i+1 issued before consuming batch i;
    // steady-state 16 loads in flight, waits at vmcnt(8) only
    if (lo < hi) {
        u32x4 A0, A1, A2, A3, A4, A5, A6, A7;
        u32x4 B0, B1, B2, B3, B4, B5, B6, B7;
        float fxA, fyA, fxB, fyB;
        int kc = 0;
        int i = lo;
        {
            const char* p  = base_of((float)i, fxA, fyA);
            const char* p2 = p + ROW_BYTES;
            ISSUE4(p,  A0, A1, A2, A3);
            ISSUE4(p2, A4, A5, A6, A7);
        }
        for (;;) {
            {
                const char* p  = base_of((float)(i + 1), fxB, fyB);
                const char* p2 = p + ROW_BYTES;
                ISSUE4(p,  B0, B1, B2, B3);
                ISSUE4(p2, B4, B5, B6, B7);
            }
            WAIT_VM8();                                   // A arrived, B in flight
            cons(A0, A1, A2, A3, A4, A5, A6, A7, fxA, fyA);
            i += 2;
            if (i >= hi) {
                WAIT_VM0();                               // drain B
                cons(B0, B1, B2, B3, B4, B5, B6, B7, fxB, fyB);
                break;
            }
            {
                const char* p  = base_of((float)i, fxA, fyA);
                const char* p2 = p + ROW_BYTES;
                ISSUE4(p,  A0, A1, A2, A3);
                ISSUE4(p2, A4, A5, A6, A7);
            }
            WAIT_VM8();                                   // B arrived, A' in flight
            cons(B0, B1, B2, B3, B4, B5, B6, B7, fxB, fyB);
            if (((++kc) & 1) == 0) flush();               // every 4 steps
        }
    }
    flush();

    // thread zo covers v = 8zo..8zo+7 (lo half) and v = 64+8zo..+7 (hi half)
    float* op = dst + (size_t)blockIdx.z * SINO + ((size_t)u_i * A_N + a) * V_N;
    float* opl = op + 8 * zo;
    float* oph = op + 64 + 8 * zo;
    *(float4*)(opl)     = make_float4(accf[0]  * scale, accf[1]  * scale, accf[2]  * scale, accf[3]  * scale);
    *(float4*)(opl + 4) = make_float4(accf[4]  * scale, accf[5]  * scale, accf[6]  * scale, accf[7]  * scale);
    *(float4*)(oph)     = make_float4(accf[8]  * scale, accf[9]  * scale, accf[10] * scale, accf[11] * scale);
    *(float4*)(oph + 4) = make_float4(accf[12] * scale, accf[13] * scale, accf[14] * scale, accf[15] * scale);
}

// ---- reduce: out = (sum of nseg partials) * DT ----
__global__ __launch_bounds__(256) void reduce_segs(
    const float4* __restrict__ p, float4* __restrict__ out, int nseg)
{
    const size_t i = (size_t)blockIdx.x * 256 + threadIdx.x;  // SINO/4 threads
    const size_t q = SINO / 4;
    float4 s = p[i];
    for (int k = 1; k < nseg; ++k) {
        const float4 b = p[i + (size_t)k * q];
        s.x += b.x; s.y += b.y; s.z += b.z; s.w += b.w;
    }
    out[i] = make_float4(s.x * DT, s.y * DT, s.z * DT, s.w * DT);
}

// ---- fallback: fp32 volume, no workspace needed ----
__global__ __launch_bounds__(256) void joseph_fwd_f32(
    const float* __restrict__ vol,
    const float* __restrict__ angles,
    float* __restrict__ out)
{
    const int zo  = threadIdx.x & 15;
    const int r   = threadIdx.x >> 4;
    const int u_i = blockIdx.x * 16 + r;
    const int a   = blockIdx.y;

    const float ang = angles[a];
    const float c = cosf(ang);
    const float s = sinf(ang);
    const float u = (float)u_i - 63.5f;
    const float xb = fmaf(-u, s, 63.5f);
    const float yb = fmaf( u, c, 63.5f);

    const float* volz = vol + 8 * zo;
    float4 accA = make_float4(0.f, 0.f, 0.f, 0.f);
    float4 accB = make_float4(0.f, 0.f, 0.f, 0.f);

    for (int i = 0; i < NSTEPS; ++i) {
        const float t  = fmaf((float)i + 0.5f, DT, -T_HALF);
        const float xi = fmaf(t, c, xb);
        const float yi = fmaf(t, s, yb);
        const float fx0f = floorf(xi);
        const float fy0f = floorf(yi);
        const int x0 = (int)fx0f;
        const int y0 = (int)fy0f;
        const float fx = xi - fx0f;
        const float fy = yi - fy0f;
        const int x1 = x0 + 1;
        const int y1 = y0 + 1;
        const float wx0 = (x0 >= 0 && x0 < W_N) ? (1.f - fx) : 0.f;
        const float wx1 = (x1 >= 0 && x1 < W_N) ? fx : 0.f;
        const float wy0 = (y0 >= 0 && y0 < H_N) ? (1.f - fy) : 0.f;
        const float wy1 = (y1 >= 0 && y1 < H_N) ? fy : 0.f;
        if ((wx0 + wx1) == 0.f || (wy0 + wy1) == 0.f) continue;
        const int cx0 = min(max(x0, 0), W_N - 1);
        const int cx1 = min(max(x1, 0), W_N - 1);
        const int cy0 = min(max(y0, 0), H_N - 1);
        const int cy1 = min(max(y1, 0), H_N - 1);
        const float* p00 = volz + ((cx0 * H_N + cy0) << 7);
        const float* p01 = volz + ((cx1 * H_N + cy0) << 7);
        const float* p10 = volz + ((cx0 * H_N + cy1) << 7);
        const float* p11 = volz + ((cx1 * H_N + cy1) << 7);
        const float4 v00a = *(const float4*)(p00);
        const float4 v00b = *(const float4*)(p00 + 4);
        const float4 v01a = *(const float4*)(p01);
        const float4 v01b = *(const float4*)(p01 + 4);
        const float4 v10a = *(const float4*)(p10);
        const float4 v10b = *(const float4*)(p10 + 4);
        const float4 v11a = *(const float4*)(p11);
        const float4 v11b = *(const float4*)(p11 + 4);
        const float w00 = wx0 * wy0, w01 = wx1 * wy0, w10 = wx0 * wy1, w11 = wx1 * wy1;
        accA.x = fmaf(w00, v00a.x, fmaf(w01, v01a.x, fmaf(w10, v10a.x, fmaf(w11, v11a.x, accA.x))));
        accA.y = fmaf(w00, v00a.y, fmaf(w01, v01a.y, fmaf(w10, v10a.y, fmaf(w11, v11a.y, accA.y))));
        accA.z = fmaf(w00, v00a.z, fmaf(w01, v01a.z, fmaf(w10, v10a.z, fmaf(w11, v11a.z, accA.z))));
        accA.w = fmaf(w00, v00a.w, fmaf(w01, v01a.w, fmaf(w10, v10a.w, fmaf(w11, v11a.w, accA.w))));
        accB.x = fmaf(w00, v00b.x, fmaf(w01, v01b.x, fmaf(w10, v10b.x, fmaf(w11, v11b.x, accB.x))));
        accB.y = fmaf(w00, v00b.y, fmaf(w01, v01b.y, fmaf(w10, v10b.y, fmaf(w11, v11b.y, accB.y))));
        accB.z = fmaf(w00, v00b.z, fmaf(w01, v01b.z, fmaf(w10, v10b.z, fmaf(w11, v11b.z, accB.z))));
        accB.w = fmaf(w00, v00b.w, fmaf(w01, v01b.w, fmaf(w10, v10b.w, fmaf(w11, v11b.w, accB.w))));
    }

    float* op = out + ((size_t)u_i * A_N + a) * V_N + 8 * zo;
    *(float4*)(op)     = make_float4(accA.x * DT, accA.y * DT, accA.z * DT, accA.w * DT);
    *(float4*)(op + 4) = make_float4(accB.x * DT, accB.y * DT, accB.z * DT, accB.w * DT);
}

extern "C" void kernel_launch(void* const* d_in, const int* in_sizes, int n_in,
                              void* d_out, int out_size, void* d_ws, size_t ws_size,
                              hipStream_t stream) {
    const float* vol    = (const float*)d_in[0];
    const float* angles = (const float*)d_in[1];
    float* out          = (float*)d_out;

    const int pad_blocks = (int)((VOLP_COLS * 16 + 255) / 256);

    if (ws_size >= VOLP_BYTES) {
        unsigned int* volp = (unsigned int*)d_ws;
        hipLaunchKernelGGL(vol_pad_f16, dim3(pad_blocks), dim3(256), 0, stream, vol, volp);

        int nseg = 0;
        if (ws_size >= VOLP_BYTES + 4 * SINO * sizeof(float))      nseg = 4;
        else if (ws_size >= VOLP_BYTES + 2 * SINO * sizeof(float)) nseg = 2;

        if (nseg) {
            float* partial = (float*)((char*)d_ws + VOLP_BYTES);
            dim3 grid(U_N / RAYS_PER_BLOCK, A_N, nseg);   // 4 x 96 x nseg, 256-thr blocks
            hipLaunchKernelGGL(joseph_fwd_inc, grid, dim3(BLOCK_THREADS), 0, stream,
                               (const unsigned short*)volp, angles, partial, 1.0f);
            hipLaunchKernelGGL(reduce_segs, dim3(SINO / 4 / 256), dim3(256), 0, stream,
                               (const float4*)partial, (float4*)out, nseg);
        } else {
            dim3 grid(U_N / RAYS_PER_BLOCK, A_N, 1);
            hipLaunchKernelGGL(joseph_fwd_inc, grid, dim3(BLOCK_THREADS), 0, stream,
                               (const unsigned short*)volp, angles, out, DT);
        }
    } else {
        dim3 grid(U_N / 16, A_N);
        hipLaunchKernelGGL(joseph_fwd_f32, grid, dim3(256), 0, stream, vol, angles, out);
    }
}

// Round 8
// 105.725 us; speedup vs baseline: 1.3302x; 1.1026x over previous
//
#include <hip/hip_runtime.h>
#include <hip/hip_fp16.h>

namespace {
constexpr int A_N = 96;
constexpr int U_N = 128;
constexpr int V_N = 128;
constexpr int W_N = 128;
constexpr int H_N = 128;
constexpr int NSTEPS = 128;
constexpr float T_HALF = 89.80256121069154f;
constexpr float DT = 1.4031650189170554f;   // 2*T/NSTEPS
constexpr float INV_DT = 1.0f / DT;
constexpr int PAD = 6;                      // zero border: covers range slop + unroll alignment
constexpr int WP = W_N + 2 * PAD;           // 140 padded columns per row
constexpr int ROW_BYTES = WP * 256;         // x-stride in bytes (f16 column = 256 B)
constexpr int ZT = 8;                       // z-threads per ray (16 z-values each)
constexpr int RAYS_PER_WAVE = 8;            // wave = 8 rays x 8 z (VALU amortized, line-minimal)
constexpr int RAYS_PER_BLOCK = 16;          // waves 0,1 = rays, waves 2,3 = same rays 2nd step-half
constexpr int BLOCK_THREADS = 256;
constexpr size_t VOLP_COLS = (size_t)WP * WP;          // 19600 columns
constexpr size_t VOLP_BYTES = VOLP_COLS * 256;         // ~5.02 MB
constexpr size_t SINO = (size_t)U_N * A_N * V_N;       // 1.57M floats
}

typedef __attribute__((ext_vector_type(4))) unsigned int u32x4;

// ---- pack two floats -> half2 bits ----
__device__ __forceinline__ unsigned int packh2(float a, float b) {
    return (unsigned int)__half_as_ushort(__float2half_rn(a)) |
           ((unsigned int)__half_as_ushort(__float2half_rn(b)) << 16);
}

// ---- pre-pass: fp32 volume -> padded f16 volume (zero border of PAD cols) ----
__global__ __launch_bounds__(256) void vol_pad_f16(
    const float* __restrict__ vol, unsigned int* __restrict__ volp)
{
    const int idx = blockIdx.x * 256 + threadIdx.x;    // WP*WP*16 threads
    if (idx >= (int)(VOLP_COLS * 16)) return;
    const int zo  = idx & 15;
    const int col = idx >> 4;
    const int yp = col % WP;
    const int xp = col / WP;
    const int x = xp - PAD;
    const int y = yp - PAD;
    uint4 o = make_uint4(0u, 0u, 0u, 0u);
    if ((unsigned)x < 128u && (unsigned)y < 128u) {
        const float* src = vol + (((size_t)x * 128 + y) << 7) + zo * 8;
        const float4 f0 = *(const float4*)(src);
        const float4 f1 = *(const float4*)(src + 4);
        o.x = packh2(f0.x, f0.y);
        o.y = packh2(f0.z, f0.w);
        o.z = packh2(f1.x, f1.y);
        o.w = packh2(f1.z, f1.w);
    }
    *(uint4*)((char*)volp + (size_t)col * 256 + zo * 16) = o;
}

// ---- issue 4 16-B loads from one column-pair base ----
#define ISSUE4(p, q0, q1, q2, q3)                                        \
    asm volatile("global_load_dwordx4 %0, %4, off\n\t"                   \
                 "global_load_dwordx4 %1, %4, off offset:128\n\t"        \
                 "global_load_dwordx4 %2, %4, off offset:256\n\t"        \
                 "global_load_dwordx4 %3, %4, off offset:384"            \
                 : "=&v"(q0), "=&v"(q1), "=&v"(q2), "=&v"(q3)            \
                 : "v"(p))

#define WAIT_VM8()  do { asm volatile("s_waitcnt vmcnt(8)" ::: "memory"); \
                         __builtin_amdgcn_sched_barrier(0); } while (0)
#define WAIT_VM0()  do { asm volatile("s_waitcnt vmcnt(0)" ::: "memory"); \
                         __builtin_amdgcn_sched_barrier(0); } while (0)

// ---- fused projector: block = 16 rays x full chord.
//      waves 0,1 = rays 0-7 / 8-15 for steps [0,64); waves 2,3 same rays [64,128).
//      8 KB LDS combine replaces the global reduce kernel.
//      XCD swizzle groups 12 consecutive angles per XCD (L2 locality). ----
__global__ __launch_bounds__(BLOCK_THREADS, 4) void joseph_fwd_fused(
    const unsigned short* __restrict__ volp,
    const float* __restrict__ angles,
    float* __restrict__ out)
{
    const int zo = threadIdx.x & (ZT - 1);        // z-group within wave
    const int rw = (threadIdx.x >> 3) & 7;        // ray within wave (0..7)
    const int wv = threadIdx.x >> 6;              // wave within block (0..3)
    const int ray = (wv & 1) * 8 + rw;            // 0..15
    const int shalf = wv >> 1;                    // step half

    // XCD-angle-grouping swizzle (bijective: 768 % 8 == 0): XCD k gets angles [12k,12k+12)
    const int lin = (int)blockIdx.x + 8 * (int)blockIdx.y;   // grid (8, 96)
    const int swz = (lin & 7) * 96 + (lin >> 3);
    const int a   = swz >> 3;
    const int xtr = swz & 7;
    // center-first u-tile order {3,4,2,5,1,6,0,7}
    const int xt = (xtr & 1) ? (4 + (xtr >> 1)) : (3 - (xtr >> 1));
    const int u_i = xt * RAYS_PER_BLOCK + ray;

    const int i0 = shalf * (NSTEPS / 2);
    const int i1 = i0 + NSTEPS / 2;

    const float ang = angles[a];
    const float cv = cosf(ang);
    const float sv = sinf(ang);
    const float up = (float)u_i - 63.5f;
    const float xb = fmaf(-up, sv, 63.5f);
    const float yb = fmaf( up, cv, 63.5f);

    // valid-step range: xi,yi in (-1,128); +-2-step slop + 1 alignment step < PAD=6
    float tlo = -2.f * T_HALF, thi = 2.f * T_HALF;
    if (fabsf(cv) > 1e-6f) {
        const float ta = (-1.f - xb) / cv, tb = (128.f - xb) / cv;
        tlo = fmaxf(tlo, fminf(ta, tb));
        thi = fminf(thi, fmaxf(ta, tb));
    } else if (xb <= -1.f || xb >= 128.f) { thi = tlo - 1.f; }
    if (fabsf(sv) > 1e-6f) {
        const float ta = (-1.f - yb) / sv, tb = (128.f - yb) / sv;
        tlo = fmaxf(tlo, fminf(ta, tb));
        thi = fminf(thi, fmaxf(ta, tb));
    } else if (yb <= -1.f || yb >= 128.f) { thi = tlo - 1.f; }
    const int ilo = (int)floorf(fmaf(tlo + T_HALF, INV_DT, -0.5f)) - 1;
    const int ihi = (int)ceilf (fmaf(thi + T_HALF, INV_DT, -0.5f)) + 1;
    int lo = min(max(ilo, i0), i1);
    int hi = min(max(ihi + 1, i0), i1);
    lo &= ~1;                                  // even-align down (pad-safe; i0 is even)
    hi = (hi + 1) & ~1;                        // even-align up (i1 even -> hi<=i1)

    const char* __restrict__ volc = (const char*)volp;
    const int laneb = zo << 4;                 // contiguous 16 B per z-thread within half-column

    __half2 hacc[8];
    float accf[16];
#pragma unroll
    for (int j = 0; j < 8; ++j) hacc[j] = __float2half2_rn(0.f);
#pragma unroll
    for (int k = 0; k < 16; ++k) accf[k] = 0.f;

    auto base_of = [&](float i_f, float& fx, float& fy) -> const char* {
        const float tf = fmaf(i_f + 0.5f, DT, -T_HALF);
        const float xi = fmaf(tf, cv, xb);
        const float yi = fmaf(tf, sv, yb);
        const float fx0 = floorf(xi);
        const float fy0 = floorf(yi);
        fx = xi - fx0;
        fy = yi - fy0;
        const int x0 = (int)fx0;
        const int y0 = (int)fy0;
        return volc + ((((x0 + PAD) * WP + (y0 + PAD)) << 8) + laneb);
    };

    auto cons = [&](u32x4 q00l, u32x4 q00h, u32x4 q01l, u32x4 q01h,
                    u32x4 q10l, u32x4 q10h, u32x4 q11l, u32x4 q11h,
                    float fx, float fy) {
        const float wx0 = 1.f - fx;
        const float wy0 = 1.f - fy;
        const __half2 w00 = __float2half2_rn(wx0 * wy0);
        const __half2 w01 = __float2half2_rn(wx0 * fy);
        const __half2 w10 = __float2half2_rn(fx  * wy0);
        const __half2 w11 = __float2half2_rn(fx  * fy);
#pragma unroll
        for (int j = 0; j < 4; ++j) {
            hacc[j] = __hfma2(w00, __builtin_bit_cast(__half2, (unsigned int)q00l[j]), hacc[j]);
            hacc[j] = __hfma2(w01, __builtin_bit_cast(__half2, (unsigned int)q01l[j]), hacc[j]);
            hacc[j] = __hfma2(w10, __builtin_bit_cast(__half2, (unsigned int)q10l[j]), hacc[j]);
            hacc[j] = __hfma2(w11, __builtin_bit_cast(__half2, (unsigned int)q11l[j]), hacc[j]);
            hacc[4 + j] = __hfma2(w00, __builtin_bit_cast(__half2, (unsigned int)q00h[j]), hacc[4 + j]);
            hacc[4 + j] = __hfma2(w01, __builtin_bit_cast(__half2, (unsigned int)q01h[j]), hacc[4 + j]);
            hacc[4 + j] = __hfma2(w10, __builtin_bit_cast(__half2, (unsigned int)q10h[j]), hacc[4 + j]);
            hacc[4 + j] = __hfma2(w11, __builtin_bit_cast(__half2, (unsigned int)q11h[j]), hacc[4 + j]);
        }
    };

    auto flush = [&]() {
#pragma unroll
        for (int j = 0; j < 8; ++j) {
            const float2 f = __half22float2(hacc[j]);
            accf[2 * j]     += f.x;
            accf[2 * j + 1] += f.y;
            hacc[j] = __float2half2_rn(0.f);
        }
    };

    // asm-pipelined main loop: batch i+1 issued before consuming batch i
    if (lo < hi) {
        u32x4 A0, A1, A2, A3, A4, A5, A6, A7;
        u32x4 B0, B1, B2, B3, B4, B5, B6, B7;
        float fxA, fyA, fxB, fyB;
        int kc = 0;
        int i = lo;
        {
            const char* p  = base_of((float)i, fxA, fyA);
            const char* p2 = p + ROW_BYTES;
            ISSUE4(p,  A0, A1, A2, A3);
            ISSUE4(p2, A4, A5, A6, A7);
        }
        for (;;) {
            {
                const char* p  = base_of((float)(i + 1), fxB, fyB);
                const char* p2 = p + ROW_BYTES;
                ISSUE4(p,  B0, B1, B2, B3);
                ISSUE4(p2, B4, B5, B6, B7);
            }
            WAIT_VM8();                                   // A arrived, B in flight
            cons(A0, A1, A2, A3, A4, A5, A6, A7, fxA, fyA);
            i += 2;
            if (i >= hi) {
                WAIT_VM0();                               // drain B
                cons(B0, B1, B2, B3, B4, B5, B6, B7, fxB, fyB);
                break;
            }
            {
                const char* p  = base_of((float)i, fxA, fyA);
                const char* p2 = p + ROW_BYTES;
                ISSUE4(p,  A0, A1, A2, A3);
                ISSUE4(p2, A4, A5, A6, A7);
            }
            WAIT_VM8();                                   // B arrived, A' in flight
            cons(B0, B1, B2, B3, B4, B5, B6, B7, fxB, fyB);
            if (((++kc) & 1) == 0) flush();               // every 4 steps
        }
    }
    flush();

    // ---- in-block combine: waves 2,3 deposit partials, waves 0,1 add + write ----
    __shared__ float part[RAYS_PER_BLOCK][V_N];           // 8 KB
    if (shalf == 1) {
        float* p0 = &part[ray][8 * zo];
        float* p1 = &part[ray][64 + 8 * zo];
        *(float4*)(p0)     = make_float4(accf[0],  accf[1],  accf[2],  accf[3]);
        *(float4*)(p0 + 4) = make_float4(accf[4],  accf[5],  accf[6],  accf[7]);
        *(float4*)(p1)     = make_float4(accf[8],  accf[9],  accf[10], accf[11]);
        *(float4*)(p1 + 4) = make_float4(accf[12], accf[13], accf[14], accf[15]);
    }
    __syncthreads();
    if (shalf == 0) {
        const float* p0 = &part[ray][8 * zo];
        const float* p1 = &part[ray][64 + 8 * zo];
        const float4 q0 = *(const float4*)(p0);
        const float4 q1 = *(const float4*)(p0 + 4);
        const float4 q2 = *(const float4*)(p1);
        const float4 q3 = *(const float4*)(p1 + 4);
        float* op = out + ((size_t)u_i * A_N + a) * V_N;
        float* opl = op + 8 * zo;
        float* oph = op + 64 + 8 * zo;
        *(float4*)(opl)     = make_float4((accf[0]  + q0.x) * DT, (accf[1]  + q0.y) * DT,
                                          (accf[2]  + q0.z) * DT, (accf[3]  + q0.w) * DT);
        *(float4*)(opl + 4) = make_float4((accf[4]  + q1.x) * DT, (accf[5]  + q1.y) * DT,
                                          (accf[6]  + q1.z) * DT, (accf[7]  + q1.w) * DT);
        *(float4*)(oph)     = make_float4((accf[8]  + q2.x) * DT, (accf[9]  + q2.y) * DT,
                                          (accf[10] + q2.z) * DT, (accf[11] + q2.w) * DT);
        *(float4*)(oph + 4) = make_float4((accf[12] + q3.x) * DT, (accf[13] + q3.y) * DT,
                                          (accf[14] + q3.z) * DT, (accf[15] + q3.w) * DT);
    }
}

// ---- fallback: fp32 volume, no workspace needed ----
__global__ __launch_bounds__(256) void joseph_fwd_f32(
    const float* __restrict__ vol,
    const float* __restrict__ angles,
    float* __restrict__ out)
{
    const int zo  = threadIdx.x & 15;
    const int r   = threadIdx.x >> 4;
    const int u_i = blockIdx.x * 16 + r;
    const int a   = blockIdx.y;

    const float ang = angles[a];
    const float c = cosf(ang);
    const float s = sinf(ang);
    const float u = (float)u_i - 63.5f;
    const float xb = fmaf(-u, s, 63.5f);
    const float yb = fmaf( u, c, 63.5f);

    const float* volz = vol + 8 * zo;
    float4 accA = make_float4(0.f, 0.f, 0.f, 0.f);
    float4 accB = make_float4(0.f, 0.f, 0.f, 0.f);

    for (int i = 0; i < NSTEPS; ++i) {
        const float t  = fmaf((float)i + 0.5f, DT, -T_HALF);
        const float xi = fmaf(t, c, xb);
        const float yi = fmaf(t, s, yb);
        const float fx0f = floorf(xi);
        const float fy0f = floorf(yi);
        const int x0 = (int)fx0f;
        const int y0 = (int)fy0f;
        const float fx = xi - fx0f;
        const float fy = yi - fy0f;
        const int x1 = x0 + 1;
        const int y1 = y0 + 1;
        const float wx0 = (x0 >= 0 && x0 < W_N) ? (1.f - fx) : 0.f;
        const float wx1 = (x1 >= 0 && x1 < W_N) ? fx : 0.f;
        const float wy0 = (y0 >= 0 && y0 < H_N) ? (1.f - fy) : 0.f;
        const float wy1 = (y1 >= 0 && y1 < H_N) ? fy : 0.f;
        if ((wx0 + wx1) == 0.f || (wy0 + wy1) == 0.f) continue;
        const int cx0 = min(max(x0, 0), W_N - 1);
        const int cx1 = min(max(x1, 0), W_N - 1);
        const int cy0 = min(max(y0, 0), H_N - 1);
        const int cy1 = min(max(y1, 0), H_N - 1);
        const float* p00 = volz + ((cx0 * H_N + cy0) << 7);
        const float* p01 = volz + ((cx1 * H_N + cy0) << 7);
        const float* p10 = volz + ((cx0 * H_N + cy1) << 7);
        const float* p11 = volz + ((cx1 * H_N + cy1) << 7);
        const float4 v00a = *(const float4*)(p00);
        const float4 v00b = *(const float4*)(p00 + 4);
        const float4 v01a = *(const float4*)(p01);
        const float4 v01b = *(const float4*)(p01 + 4);
        const float4 v10a = *(const float4*)(p10);
        const float4 v10b = *(const float4*)(p10 + 4);
        const float4 v11a = *(const float4*)(p11);
        const float4 v11b = *(const float4*)(p11 + 4);
        const float w00 = wx0 * wy0, w01 = wx1 * wy0, w10 = wx0 * wy1, w11 = wx1 * wy1;
        accA.x = fmaf(w00, v00a.x, fmaf(w01, v01a.x, fmaf(w10, v10a.x, fmaf(w11, v11a.x, accA.x))));
        accA.y = fmaf(w00, v00a.y, fmaf(w01, v01a.y, fmaf(w10, v10a.y, fmaf(w11, v11a.y, accA.y))));
        accA.z = fmaf(w00, v00a.z, fmaf(w01, v01a.z, fmaf(w10, v10a.z, fmaf(w11, v11a.z, accA.z))));
        accA.w = fmaf(w00, v00a.w, fmaf(w01, v01a.w, fmaf(w10, v10a.w, fmaf(w11, v11a.w, accA.w))));
        accB.x = fmaf(w00, v00b.x, fmaf(w01, v01b.x, fmaf(w10, v10b.x, fmaf(w11, v11b.x, accB.x))));
        accB.y = fmaf(w00, v00b.y, fmaf(w01, v01b.y, fmaf(w10, v10b.y, fmaf(w11, v11b.y, accB.y))));
        accB.z = fmaf(w00, v00b.z, fmaf(w01, v01b.z, fmaf(w10, v10b.z, fmaf(w11, v11b.z, accB.z))));
        accB.w = fmaf(w00, v00b.w, fmaf(w01, v01b.w, fmaf(w10, v10b.w, fmaf(w11, v11b.w, accB.w))));
    }

    float* op = out + ((size_t)u_i * A_N + a) * V_N + 8 * zo;
    *(float4*)(op)     = make_float4(accA.x * DT, accA.y * DT, accA.z * DT, accA.w * DT);
    *(float4*)(op + 4) = make_float4(accB.x * DT, accB.y * DT, accB.z * DT, accB.w * DT);
}

extern "C" void kernel_launch(void* const* d_in, const int* in_sizes, int n_in,
                              void* d_out, int out_size, void* d_ws, size_t ws_size,
                              hipStream_t stream) {
    const float* vol    = (const float*)d_in[0];
    const float* angles = (const float*)d_in[1];
    float* out          = (float*)d_out;

    const int pad_blocks = (int)((VOLP_COLS * 16 + 255) / 256);

    if (ws_size >= VOLP_BYTES) {
        unsigned int* volp = (unsigned int*)d_ws;
        hipLaunchKernelGGL(vol_pad_f16, dim3(pad_blocks), dim3(256), 0, stream, vol, volp);
        dim3 grid(U_N / RAYS_PER_BLOCK, A_N);   // 8 x 96 = 768 blocks, 256 thr
        hipLaunchKernelGGL(joseph_fwd_fused, grid, dim3(BLOCK_THREADS), 0, stream,
                           (const unsigned short*)volp, angles, out);
    } else {
        dim3 grid(U_N / 16, A_N);
        hipLaunchKernelGGL(joseph_fwd_f32, grid, dim3(256), 0, stream, vol, angles, out);
    }
}